// Round 1
// baseline (759.328 us; speedup 1.0000x reference)
//
#include <hip/hip_runtime.h>

#define HW_IN 1020
#define P1 511
#define H2 501
#define P2 251
#define H3 249
#define OUT_SPK 0
#define OUT_POT (15*2*249*249)
#define OUT_WIN (2*15*2*249*249)

// ---------------- K0: first-spike time of the input -------------------------
__global__ __launch_bounds__(256) void k_tau_in(const float* __restrict__ in,
                                                unsigned char* __restrict__ tau) {
    const int n = 2 * HW_IN * HW_IN;
    int i = blockIdx.x * 256 + threadIdx.x;
    if (i >= n) return;
    float s = 0.f;
#pragma unroll
    for (int t = 0; t < 15; ++t) s += in[(size_t)t * n + i];
    // cumulative binary input: #active steps = 15 - tau  (exact fp32 sum)
    tau[i] = (unsigned char)(15 - (int)(s + 0.5f));
}

// ---------------- K1: conv1 (5x5, pad2) + fire(5.0) + pool(2,2,pad1) --------
// Output: tau1p[4][511][511] = first t where any pool-window spk1 fires.
__global__ __launch_bounds__(256) void k_conv1_pool(const unsigned char* __restrict__ tin,
                                                    const float* __restrict__ w1,
                                                    unsigned char* __restrict__ t1p) {
    const int c4 = blockIdx.z;
    const int X0 = blockIdx.x * 16, Y0 = blockIdx.y * 16;
    __shared__ unsigned char sm[2][36][36];
    __shared__ float sw[2][5][5];
    const int tid = threadIdx.y * 16 + threadIdx.x;
    if (tid < 50) {
        int cin = tid / 25, r = tid % 25;
        sw[cin][r / 5][r % 5] = w1[(c4 * 2 + cin) * 25 + r];
    }
    for (int s = tid; s < 2 * 36 * 36; s += 256) {
        int cin = s / (36 * 36), rem = s % (36 * 36), rr = rem / 36, cc = rem % 36;
        int y = 2 * Y0 - 3 + rr, x = 2 * X0 - 3 + cc;
        unsigned char v = 15;
        if (y >= 0 && y < HW_IN && x >= 0 && x < HW_IN)
            v = tin[(cin * HW_IN + y) * HW_IN + x];
        sm[cin][rr][cc] = v;
    }
    __syncthreads();
    const int py = Y0 + threadIdx.y, px = X0 + threadIdx.x;
    if (py >= P1 || px >= P1) return;

    // registerize the 2x6x6 tau region this thread needs
    int rg[2][6][6];
#pragma unroll
    for (int cin = 0; cin < 2; ++cin)
#pragma unroll
        for (int rr = 0; rr < 6; ++rr)
#pragma unroll
            for (int cc = 0; cc < 6; ++cc)
                rg[cin][rr][cc] = sm[cin][2 * threadIdx.y + rr][2 * threadIdx.x + cc];
    float wr[2][5][5];
#pragma unroll
    for (int cin = 0; cin < 2; ++cin)
#pragma unroll
        for (int ky = 0; ky < 5; ++ky)
#pragma unroll
            for (int kx = 0; kx < 5; ++kx) wr[cin][ky][kx] = sw[cin][ky][kx];

    const bool va0 = (py >= 1);         // window row 2*py-1 valid
    const bool va1 = (py <= 509);       // window row 2*py   valid (< 1020)
    const bool vb0 = (px >= 1);
    const bool vb1 = (px <= 509);

    // binary search smallest t in [0,15] with any valid window pot >= 5
    int lo = 0, hi = 15;
    while (lo < hi) {
        const int mid = (lo + hi) >> 1;
        bool any = false;
#pragma unroll
        for (int a = 0; a < 2; ++a) {
#pragma unroll
            for (int b = 0; b < 2; ++b) {
                const bool valid = (a ? va1 : va0) && (b ? vb1 : vb0);
                float s = 0.f;
#pragma unroll
                for (int cin = 0; cin < 2; ++cin)
#pragma unroll
                    for (int ky = 0; ky < 5; ++ky)
#pragma unroll
                        for (int kx = 0; kx < 5; ++kx)
                            s += (rg[cin][a + ky][b + kx] <= mid) ? wr[cin][ky][kx] : 0.f;
                any = any || (valid && s >= 5.0f);
            }
        }
        if (any) hi = mid; else lo = mid + 1;
    }
    t1p[(c4 * P1 + py) * P1 + px] = (unsigned char)lo;
}

// ---------------- K2: conv2 (15x15, pad2) + fire(50) + pool ------------------
// Incremental over t: pot2(t) = pot2(t-1) + conv(delta spikes at t).
// Block: (8,16) threads, tile = 16 rows x 32 cols of pooled output, grid.z=oc.
__global__ __launch_bounds__(128) void k_conv2_pool(const unsigned char* __restrict__ t1p,
                                                    const float* __restrict__ w2,
                                                    unsigned char* __restrict__ t2p) {
    const int oc = blockIdx.z;
    const int X0 = blockIdx.x * 32, Y0 = blockIdx.y * 16;
    __shared__ unsigned char stau[4][47][80];
    __shared__ unsigned char sdel[4][47][80];
    __shared__ float sw[4][15][16];
    __shared__ int undone;
    const int tx = threadIdx.x, ty = threadIdx.y;
    const int tid = ty * 8 + tx;

    for (int s = tid; s < 4 * 225; s += 128) {
        int c = s / 225, r = s % 225;
        sw[c][r / 15][r % 15] = w2[(oc * 4 + c) * 225 + r];
    }
    for (int s = tid; s < 4 * 47 * 80; s += 128) {
        int c = s / (47 * 80), rem = s % (47 * 80), rr = rem / 80, cc = rem % 80;
        int y = 2 * Y0 - 3 + rr, x = 2 * X0 - 3 + cc;
        unsigned char v = 15;
        if (y >= 0 && y < P1 && x >= 0 && x < P1)
            v = t1p[(c * P1 + y) * P1 + x];
        stau[c][rr][cc] = v;
    }

    const int py = Y0 + ty;
    const int pxb = X0 + tx * 4;       // 4 pooled outputs per thread
    float acc[4][4];                    // [j][a*2+b] window potentials
#pragma unroll
    for (int j = 0; j < 4; ++j) { acc[j][0] = acc[j][1] = acc[j][2] = acc[j][3] = 0.f; }
    int taup[4] = {15, 15, 15, 15};
    bool vj[4], vb0[4];
#pragma unroll
    for (int j = 0; j < 4; ++j) {
        vj[j] = (py < P2) && (pxb + j < P2);
        vb0[j] = (pxb + j >= 1);
    }
    const bool va0 = (py >= 1);

    __syncthreads();
    for (int t = 0; t < 15; ++t) {
        if (tid == 0) undone = 0;
        __syncthreads();
        bool act = false;
#pragma unroll
        for (int j = 0; j < 4; ++j) act |= (vj[j] && taup[j] == 15);
        if (act) undone = 1;
        __syncthreads();
        if (undone == 0) break;
        // build delta tile (tau == t) as bytes {0,1} via SWAR, no cross-byte borrow
        {
            const unsigned int rep = 0x01010101u * (unsigned)t;
            const unsigned int* src = (const unsigned int*)&stau[0][0][0];
            unsigned int* dst = (unsigned int*)&sdel[0][0][0];
            for (int s = tid; s < (4 * 47 * 80) / 4; s += 128) {
                unsigned int x = src[s] ^ rep;
                unsigned int y = (x | 0x80808080u) - 0x01010101u;
                dst[s] = (~y & 0x80808080u) >> 7;
            }
        }
        __syncthreads();
        if (act) {
#pragma clang loop unroll(disable)
            for (int c = 0; c < 4; ++c) {
#pragma clang loop unroll(disable)
                for (int u = 0; u < 16; ++u) {          // union tap rows: a+ky in [0,15]
                    const int rr = 2 * ty + u;
                    const unsigned int* rp = (const unsigned int*)&sdel[c][rr][0] + 2 * tx;
                    unsigned int d[6];
#pragma unroll
                    for (int q = 0; q < 6; ++q) d[q] = rp[q];
                    float f[24];
#pragma unroll
                    for (int q = 0; q < 6; ++q) {
                        f[4 * q + 0] = (float)(d[q] & 0xFFu);
                        f[4 * q + 1] = (float)((d[q] >> 8) & 0xFFu);
                        f[4 * q + 2] = (float)((d[q] >> 16) & 0xFFu);
                        f[4 * q + 3] = (float)(d[q] >> 24);
                    }
#pragma unroll
                    for (int a = 0; a < 2; ++a) {
                        const int ky = u - a;
                        if (ky < 0 || ky >= 15) continue;
                        const float* wrow = &sw[c][ky][0];
#pragma unroll
                        for (int kx = 0; kx < 15; ++kx) {
                            const float wv = wrow[kx];
#pragma unroll
                            for (int j = 0; j < 4; ++j) {
                                acc[j][a * 2 + 0] += wv * f[2 * j + 0 + kx];
                                acc[j][a * 2 + 1] += wv * f[2 * j + 1 + kx];
                            }
                        }
                    }
                }
            }
#pragma unroll
            for (int j = 0; j < 4; ++j) {
                if (vj[j] && taup[j] == 15) {
                    bool fired = false;
                    fired |= (va0 && vb0[j] && acc[j][0] >= 50.f);
                    fired |= (va0 &&           acc[j][1] >= 50.f);
                    fired |= (       vb0[j] && acc[j][2] >= 50.f);
                    fired |= (                 acc[j][3] >= 50.f);
                    if (fired) taup[j] = t;
                }
            }
        }
        __syncthreads();
    }
#pragma unroll
    for (int j = 0; j < 4; ++j)
        if (vj[j]) t2p[(oc * P2 + py) * P2 + pxb + j] = (unsigned char)taup[j];
}

// ---------------- K3: conv3 (7x7, pad2) + fire(40) + outputs + total --------
__global__ __launch_bounds__(256) void k_conv3_out(const unsigned char* __restrict__ t2p,
                                                   const float* __restrict__ w3,
                                                   float* __restrict__ out,
                                                   float* __restrict__ total) {
    const int oc = blockIdx.z;
    const int X0 = blockIdx.x * 16, Y0 = blockIdx.y * 16;
    __shared__ unsigned char st[8][22][24];
    __shared__ float sw[8][7][7];
    const int tid = threadIdx.y * 16 + threadIdx.x;
    for (int i = tid; i < 8 * 49; i += 256) {
        int c = i / 49, r = i % 49;
        sw[c][r / 7][r % 7] = w3[(oc * 8 + c) * 49 + r];
    }
    for (int i = tid; i < 8 * 22 * 24; i += 256) {
        int c = i / (22 * 24), rem = i % (22 * 24), rr = rem / 24, cc = rem % 24;
        int y = Y0 - 2 + rr, x = X0 - 2 + cc;
        unsigned char v = 15;
        if (y >= 0 && y < P2 && x >= 0 && x < P2)
            v = t2p[(c * P2 + y) * P2 + x];
        st[c][rr][cc] = v;
    }
    __syncthreads();
    const int oy = Y0 + threadIdx.y, ox = X0 + threadIdx.x;
    if (oy >= H3 || ox >= H3) return;
    float s[15];
#pragma unroll
    for (int t = 0; t < 15; ++t) s[t] = 0.f;
    for (int c = 0; c < 8; ++c) {
#pragma unroll
        for (int ky = 0; ky < 7; ++ky) {
#pragma unroll
            for (int kx = 0; kx < 7; ++kx) {
                const int tv = st[c][threadIdx.y + ky][threadIdx.x + kx];
                const float wv = sw[c][ky][kx];
#pragma unroll
                for (int t = 0; t < 15; ++t) s[t] += (tv <= t) ? wv : 0.f;
            }
        }
    }
    int n = 0;
    float S = 0.f, M = 0.f;
    const int base = (oc * H3 + oy) * H3 + ox;
#pragma unroll
    for (int t = 0; t < 15; ++t) {
        const bool sp = (s[t] >= 40.f);
        const float pv = sp ? s[t] : 0.f;
        n += sp ? 1 : 0;
        S += pv;
        M = fmaxf(M, pv);
        out[OUT_SPK + t * (2 * H3 * H3) + base] = sp ? 1.f : 0.f;
        out[OUT_POT + t * (2 * H3 * H3) + base] = pv;
    }
    // total = sum_t trunc + (#spikes) * (max trunc) * (15 - #spikes)
    total[base] = S + (float)n * (M * (float)(15 - n));
}

// ---------------- K4: k=2 winners with r=5 columnar inhibition --------------
__global__ __launch_bounds__(256) void k_winners(const float* __restrict__ total,
                                                 float* __restrict__ out) {
    const int N = 2 * H3 * H3;
    __shared__ float bv[256];
    __shared__ int bi[256];
    __shared__ int winfo[4]; // c, y, x, valid
    int c0 = 0, y0 = 0, x0 = 0, valid0 = 0;
    for (int k = 0; k < 2; ++k) {
        float best = -1.f;
        int bidx = 0x7FFFFFFF;
        for (int i = threadIdx.x; i < N; i += 256) {
            if (k == 1 && valid0) {  // inhibition: same channel AND |dy|<=5 AND |dx|<=5
                int ci = i / (H3 * H3), rem = i % (H3 * H3), yi = rem / H3, xi = rem % H3;
                if (ci == c0 && yi >= y0 - 5 && yi <= y0 + 5 && xi >= x0 - 5 && xi <= x0 + 5)
                    continue;
            }
            float v = total[i];
            if (v > best || (v == best && i < bidx)) { best = v; bidx = i; }
        }
        bv[threadIdx.x] = best;
        bi[threadIdx.x] = bidx;
        __syncthreads();
        if (threadIdx.x == 0) {
            float B = bv[0];
            int I = bi[0];
            for (int j = 1; j < 256; ++j)
                if (bv[j] > B || (bv[j] == B && bi[j] < I)) { B = bv[j]; I = bi[j]; }
            const bool valid = (B > 0.f);
            const int c = I / (H3 * H3), rem = I % (H3 * H3), y = rem / H3, x = rem % H3;
            out[OUT_WIN + k * 3 + 0] = valid ? (float)c : -1.f;
            out[OUT_WIN + k * 3 + 1] = valid ? (float)y : -1.f;
            out[OUT_WIN + k * 3 + 2] = valid ? (float)x : -1.f;
            winfo[0] = c; winfo[1] = y; winfo[2] = x; winfo[3] = valid ? 1 : 0;
        }
        __syncthreads();
        c0 = winfo[0]; y0 = winfo[1]; x0 = winfo[2]; valid0 = winfo[3];
        __syncthreads();
    }
}

extern "C" void kernel_launch(void* const* d_in, const int* in_sizes, int n_in,
                              void* d_out, int out_size, void* d_ws, size_t ws_size,
                              hipStream_t stream) {
    (void)in_sizes; (void)n_in; (void)out_size; (void)ws_size;
    const float* inp = (const float*)d_in[0];
    const float* w1 = (const float*)d_in[1];
    const float* w2 = (const float*)d_in[2];
    const float* w3 = (const float*)d_in[3];
    float* out = (float*)d_out;
    char* ws = (char*)d_ws;

    unsigned char* tau_in = (unsigned char*)ws;                       // 2,080,800 B
    unsigned char* t1p = (unsigned char*)(ws + 2 * HW_IN * HW_IN);    // 1,044,484 B
    unsigned char* t2p = t1p + 4 * P1 * P1;                           //   504,008 B
    size_t tot_off = (size_t)(2 * HW_IN * HW_IN) + 4 * P1 * P1 + 8 * P2 * P2;
    tot_off = (tot_off + 15) & ~(size_t)15;
    float* total = (float*)(ws + tot_off);                            //   496,008 B

    k_tau_in<<<dim3((2 * HW_IN * HW_IN + 255) / 256), dim3(256), 0, stream>>>(inp, tau_in);
    k_conv1_pool<<<dim3(32, 32, 4), dim3(16, 16), 0, stream>>>(tau_in, w1, t1p);
    k_conv2_pool<<<dim3(8, 16, 8), dim3(8, 16), 0, stream>>>(t1p, w2, t2p);
    k_conv3_out<<<dim3(16, 16, 2), dim3(16, 16), 0, stream>>>(t2p, w3, out, total);
    k_winners<<<dim3(1), dim3(256), 0, stream>>>(total, out);
}

// Round 2
// 465.295 us; speedup vs baseline: 1.6319x; 1.6319x over previous
//
#include <hip/hip_runtime.h>

#define HW_IN 1020
#define P1 511
#define H2 501
#define P2 251
#define H3 249
#define OUT_SPK 0
#define OUT_POT (15*2*249*249)
#define OUT_WIN (2*15*2*249*249)

// ---------------- K0: first-spike time of the input -------------------------
__global__ __launch_bounds__(256) void k_tau_in(const float* __restrict__ in,
                                                unsigned char* __restrict__ tau) {
    const int n = 2 * HW_IN * HW_IN;
    int i = blockIdx.x * 256 + threadIdx.x;
    if (i >= n) return;
    float s = 0.f;
#pragma unroll
    for (int t = 0; t < 15; ++t) s += in[(size_t)t * n + i];
    // cumulative binary input: #active steps = 15 - tau  (exact fp32 sum)
    tau[i] = (unsigned char)(15 - (int)(s + 0.5f));
}

// ---------------- K1: conv1 (5x5, pad2) + fire(5.0) + pool(2,2,pad1) --------
// Output: tau1p[4][511][511] = first t where any pool-window spk1 fires.
__global__ __launch_bounds__(256) void k_conv1_pool(const unsigned char* __restrict__ tin,
                                                    const float* __restrict__ w1,
                                                    unsigned char* __restrict__ t1p) {
    const int c4 = blockIdx.z;
    const int X0 = blockIdx.x * 16, Y0 = blockIdx.y * 16;
    __shared__ unsigned char sm[2][36][36];
    __shared__ float sw[2][5][5];
    const int tid = threadIdx.y * 16 + threadIdx.x;
    if (tid < 50) {
        int cin = tid / 25, r = tid % 25;
        sw[cin][r / 5][r % 5] = w1[(c4 * 2 + cin) * 25 + r];
    }
    for (int s = tid; s < 2 * 36 * 36; s += 256) {
        int cin = s / (36 * 36), rem = s % (36 * 36), rr = rem / 36, cc = rem % 36;
        int y = 2 * Y0 - 3 + rr, x = 2 * X0 - 3 + cc;
        unsigned char v = 15;
        if (y >= 0 && y < HW_IN && x >= 0 && x < HW_IN)
            v = tin[(cin * HW_IN + y) * HW_IN + x];
        sm[cin][rr][cc] = v;
    }
    __syncthreads();
    const int py = Y0 + threadIdx.y, px = X0 + threadIdx.x;
    if (py >= P1 || px >= P1) return;

    // registerize the 2x6x6 tau region this thread needs
    int rg[2][6][6];
#pragma unroll
    for (int cin = 0; cin < 2; ++cin)
#pragma unroll
        for (int rr = 0; rr < 6; ++rr)
#pragma unroll
            for (int cc = 0; cc < 6; ++cc)
                rg[cin][rr][cc] = sm[cin][2 * threadIdx.y + rr][2 * threadIdx.x + cc];
    float wr[2][5][5];
#pragma unroll
    for (int cin = 0; cin < 2; ++cin)
#pragma unroll
        for (int ky = 0; ky < 5; ++ky)
#pragma unroll
            for (int kx = 0; kx < 5; ++kx) wr[cin][ky][kx] = sw[cin][ky][kx];

    const bool va0 = (py >= 1);         // window row 2*py-1 valid
    const bool va1 = (py <= 509);       // window row 2*py   valid (< 1020)
    const bool vb0 = (px >= 1);
    const bool vb1 = (px <= 509);

    // binary search smallest t in [0,15] with any valid window pot >= 5
    int lo = 0, hi = 15;
    while (lo < hi) {
        const int mid = (lo + hi) >> 1;
        bool any = false;
#pragma unroll
        for (int a = 0; a < 2; ++a) {
#pragma unroll
            for (int b = 0; b < 2; ++b) {
                const bool valid = (a ? va1 : va0) && (b ? vb1 : vb0);
                float s = 0.f;
#pragma unroll
                for (int cin = 0; cin < 2; ++cin)
#pragma unroll
                    for (int ky = 0; ky < 5; ++ky)
#pragma unroll
                        for (int kx = 0; kx < 5; ++kx)
                            s += (rg[cin][a + ky][b + kx] <= mid) ? wr[cin][ky][kx] : 0.f;
                any = any || (valid && s >= 5.0f);
            }
        }
        if (any) hi = mid; else lo = mid + 1;
    }
    t1p[(c4 * P1 + py) * P1 + px] = (unsigned char)lo;
}

// ---------------- K2: conv2 (15x15, pad2) + fire(50) + pool ------------------
// Incremental over t: pot2(t) = pot2(t-1) + conv(delta spikes at t).
// Block: (8,16) threads, tile = 16 rows x 32 cols of pooled output, grid.z=oc.
__global__ __launch_bounds__(128) void k_conv2_pool(const unsigned char* __restrict__ t1p,
                                                    const float* __restrict__ w2,
                                                    unsigned char* __restrict__ t2p) {
    const int oc = blockIdx.z;
    const int X0 = blockIdx.x * 32, Y0 = blockIdx.y * 16;
    __shared__ unsigned char stau[4][47][80];
    __shared__ unsigned char sdel[4][47][80];
    __shared__ float sw[4][15][16];
    __shared__ int undone;
    const int tx = threadIdx.x, ty = threadIdx.y;
    const int tid = ty * 8 + tx;

    for (int s = tid; s < 4 * 225; s += 128) {
        int c = s / 225, r = s % 225;
        sw[c][r / 15][r % 15] = w2[(oc * 4 + c) * 225 + r];
    }
    for (int s = tid; s < 4 * 47 * 80; s += 128) {
        int c = s / (47 * 80), rem = s % (47 * 80), rr = rem / 80, cc = rem % 80;
        int y = 2 * Y0 - 3 + rr, x = 2 * X0 - 3 + cc;
        unsigned char v = 15;
        if (y >= 0 && y < P1 && x >= 0 && x < P1)
            v = t1p[(c * P1 + y) * P1 + x];
        stau[c][rr][cc] = v;
    }

    const int py = Y0 + ty;
    const int pxb = X0 + tx * 4;       // 4 pooled outputs per thread
    float acc[4][4];                    // [j][a*2+b] window potentials
#pragma unroll
    for (int j = 0; j < 4; ++j) { acc[j][0] = acc[j][1] = acc[j][2] = acc[j][3] = 0.f; }
    int taup[4] = {15, 15, 15, 15};
    bool vj[4], vb0[4];
#pragma unroll
    for (int j = 0; j < 4; ++j) {
        vj[j] = (py < P2) && (pxb + j < P2);
        vb0[j] = (pxb + j >= 1);
    }
    const bool va0 = (py >= 1);

    __syncthreads();
    for (int t = 0; t < 15; ++t) {
        if (tid == 0) undone = 0;
        __syncthreads();
        bool act = false;
#pragma unroll
        for (int j = 0; j < 4; ++j) act |= (vj[j] && taup[j] == 15);
        if (act) undone = 1;
        __syncthreads();
        if (undone == 0) break;
        // build delta tile (tau == t) as bytes {0,1} via SWAR, no cross-byte borrow
        {
            const unsigned int rep = 0x01010101u * (unsigned)t;
            const unsigned int* src = (const unsigned int*)&stau[0][0][0];
            unsigned int* dst = (unsigned int*)&sdel[0][0][0];
            for (int s = tid; s < (4 * 47 * 80) / 4; s += 128) {
                unsigned int x = src[s] ^ rep;
                unsigned int y = (x | 0x80808080u) - 0x01010101u;
                dst[s] = (~y & 0x80808080u) >> 7;
            }
        }
        __syncthreads();
        if (act) {
#pragma clang loop unroll(disable)
            for (int c = 0; c < 4; ++c) {
#pragma clang loop unroll(disable)
                for (int u = 0; u < 16; ++u) {          // union tap rows: a+ky in [0,15]
                    const int rr = 2 * ty + u;
                    const unsigned int* rp = (const unsigned int*)&sdel[c][rr][0] + 2 * tx;
                    unsigned int d[6];
#pragma unroll
                    for (int q = 0; q < 6; ++q) d[q] = rp[q];
                    float f[24];
#pragma unroll
                    for (int q = 0; q < 6; ++q) {
                        f[4 * q + 0] = (float)(d[q] & 0xFFu);
                        f[4 * q + 1] = (float)((d[q] >> 8) & 0xFFu);
                        f[4 * q + 2] = (float)((d[q] >> 16) & 0xFFu);
                        f[4 * q + 3] = (float)(d[q] >> 24);
                    }
#pragma unroll
                    for (int a = 0; a < 2; ++a) {
                        const int ky = u - a;
                        if (ky < 0 || ky >= 15) continue;
                        const float* wrow = &sw[c][ky][0];
#pragma unroll
                        for (int kx = 0; kx < 15; ++kx) {
                            const float wv = wrow[kx];
#pragma unroll
                            for (int j = 0; j < 4; ++j) {
                                acc[j][a * 2 + 0] += wv * f[2 * j + 0 + kx];
                                acc[j][a * 2 + 1] += wv * f[2 * j + 1 + kx];
                            }
                        }
                    }
                }
            }
#pragma unroll
            for (int j = 0; j < 4; ++j) {
                if (vj[j] && taup[j] == 15) {
                    bool fired = false;
                    fired |= (va0 && vb0[j] && acc[j][0] >= 50.f);
                    fired |= (va0 &&           acc[j][1] >= 50.f);
                    fired |= (       vb0[j] && acc[j][2] >= 50.f);
                    fired |= (                 acc[j][3] >= 50.f);
                    if (fired) taup[j] = t;
                }
            }
        }
        __syncthreads();
    }
#pragma unroll
    for (int j = 0; j < 4; ++j)
        if (vj[j]) t2p[(oc * P2 + py) * P2 + pxb + j] = (unsigned char)taup[j];
}

// ---------------- K3: conv3 (7x7, pad2) + fire(40) + outputs + total --------
__global__ __launch_bounds__(256) void k_conv3_out(const unsigned char* __restrict__ t2p,
                                                   const float* __restrict__ w3,
                                                   float* __restrict__ out,
                                                   float* __restrict__ total) {
    const int oc = blockIdx.z;
    const int X0 = blockIdx.x * 16, Y0 = blockIdx.y * 16;
    __shared__ unsigned char st[8][22][24];
    __shared__ float sw[8][7][7];
    const int tid = threadIdx.y * 16 + threadIdx.x;
    for (int i = tid; i < 8 * 49; i += 256) {
        int c = i / 49, r = i % 49;
        sw[c][r / 7][r % 7] = w3[(oc * 8 + c) * 49 + r];
    }
    for (int i = tid; i < 8 * 22 * 24; i += 256) {
        int c = i / (22 * 24), rem = i % (22 * 24), rr = rem / 24, cc = rem % 24;
        int y = Y0 - 2 + rr, x = X0 - 2 + cc;
        unsigned char v = 15;
        if (y >= 0 && y < P2 && x >= 0 && x < P2)
            v = t2p[(c * P2 + y) * P2 + x];
        st[c][rr][cc] = v;
    }
    __syncthreads();
    const int oy = Y0 + threadIdx.y, ox = X0 + threadIdx.x;
    if (oy >= H3 || ox >= H3) return;
    float s[15];
#pragma unroll
    for (int t = 0; t < 15; ++t) s[t] = 0.f;
    for (int c = 0; c < 8; ++c) {
#pragma unroll
        for (int ky = 0; ky < 7; ++ky) {
#pragma unroll
            for (int kx = 0; kx < 7; ++kx) {
                const int tv = st[c][threadIdx.y + ky][threadIdx.x + kx];
                const float wv = sw[c][ky][kx];
#pragma unroll
                for (int t = 0; t < 15; ++t) s[t] += (tv <= t) ? wv : 0.f;
            }
        }
    }
    int n = 0;
    float S = 0.f, M = 0.f;
    const int base = (oc * H3 + oy) * H3 + ox;
#pragma unroll
    for (int t = 0; t < 15; ++t) {
        const bool sp = (s[t] >= 40.f);
        const float pv = sp ? s[t] : 0.f;
        n += sp ? 1 : 0;
        S += pv;
        M = fmaxf(M, pv);
        out[OUT_SPK + t * (2 * H3 * H3) + base] = sp ? 1.f : 0.f;
        out[OUT_POT + t * (2 * H3 * H3) + base] = pv;
    }
    // total = sum_t trunc + (#spikes) * (max trunc) * (15 - #spikes)
    total[base] = S + (float)n * (M * (float)(15 - n));
}

// ---------------- K4: k=2 winners, grid-parallel packed atomicMax -----------
// total >= 0 always, so fp32 bit pattern is order-preserving. Pack
// (val_bits << 32) | (0xFFFFFFFF - idx): u64 max == (max val, first idx).
__device__ __forceinline__ unsigned long long pack_wi(float v, int i) {
    return ((unsigned long long)__float_as_uint(v) << 32) |
           (unsigned long long)(0xFFFFFFFFu - (unsigned)i);
}

__global__ __launch_bounds__(256) void k_win_pass(const float* __restrict__ total,
                                                  unsigned long long* __restrict__ state,
                                                  int pass) {
    const int N = 2 * H3 * H3;
    int c0 = -1, y0 = 0, x0 = 0;
    bool inh = false;
    if (pass == 1) {
        const unsigned long long s0 = state[0];
        const float v0 = __uint_as_float((unsigned)(s0 >> 32));
        if (v0 > 0.f) {
            const unsigned i0 = 0xFFFFFFFFu - (unsigned)(s0 & 0xFFFFFFFFu);
            c0 = (int)(i0 / (H3 * H3));
            const int rem = (int)(i0 % (H3 * H3));
            y0 = rem / H3; x0 = rem % H3;
            inh = true;
        }
    }
    unsigned long long best = 0;
    for (int i = blockIdx.x * 256 + threadIdx.x; i < N; i += gridDim.x * 256) {
        if (inh) {
            const int ci = i / (H3 * H3), rem = i % (H3 * H3);
            const int yi = rem / H3, xi = rem % H3;
            if (ci == c0 && yi >= y0 - 5 && yi <= y0 + 5 && xi >= x0 - 5 && xi <= x0 + 5)
                continue;
        }
        const unsigned long long p = pack_wi(total[i], i);
        if (p > best) best = p;
    }
#pragma unroll
    for (int off = 32; off; off >>= 1) {
        const unsigned long long o = __shfl_down(best, off, 64);
        if (o > best) best = o;
    }
    if ((threadIdx.x & 63) == 0)
        atomicMax(&state[pass], best);
}

__global__ void k_win_finish(const unsigned long long* __restrict__ state,
                             float* __restrict__ out) {
    const int k = threadIdx.x;
    if (k >= 2) return;
    const unsigned long long s = state[k];
    const float v = __uint_as_float((unsigned)(s >> 32));
    const bool valid = (v > 0.f);
    const unsigned i = 0xFFFFFFFFu - (unsigned)(s & 0xFFFFFFFFu);
    const int c = (int)(i / (H3 * H3));
    const int rem = (int)(i % (H3 * H3));
    const int y = rem / H3, x = rem % H3;
    out[OUT_WIN + k * 3 + 0] = valid ? (float)c : -1.f;
    out[OUT_WIN + k * 3 + 1] = valid ? (float)y : -1.f;
    out[OUT_WIN + k * 3 + 2] = valid ? (float)x : -1.f;
}

extern "C" void kernel_launch(void* const* d_in, const int* in_sizes, int n_in,
                              void* d_out, int out_size, void* d_ws, size_t ws_size,
                              hipStream_t stream) {
    (void)in_sizes; (void)n_in; (void)out_size; (void)ws_size;
    const float* inp = (const float*)d_in[0];
    const float* w1 = (const float*)d_in[1];
    const float* w2 = (const float*)d_in[2];
    const float* w3 = (const float*)d_in[3];
    float* out = (float*)d_out;
    char* ws = (char*)d_ws;

    unsigned char* tau_in = (unsigned char*)ws;                       // 2,080,800 B
    unsigned char* t1p = (unsigned char*)(ws + 2 * HW_IN * HW_IN);    // 1,044,484 B
    unsigned char* t2p = t1p + 4 * P1 * P1;                           //   504,008 B
    size_t tot_off = (size_t)(2 * HW_IN * HW_IN) + 4 * P1 * P1 + 8 * P2 * P2;
    tot_off = (tot_off + 15) & ~(size_t)15;
    float* total = (float*)(ws + tot_off);                            //   496,008 B
    unsigned long long* win_state =
        (unsigned long long*)(ws + tot_off + (size_t)2 * H3 * H3 * 4); // 16 B

    hipMemsetAsync(win_state, 0, 2 * sizeof(unsigned long long), stream);
    k_tau_in<<<dim3((2 * HW_IN * HW_IN + 255) / 256), dim3(256), 0, stream>>>(inp, tau_in);
    k_conv1_pool<<<dim3(32, 32, 4), dim3(16, 16), 0, stream>>>(tau_in, w1, t1p);
    k_conv2_pool<<<dim3(8, 16, 8), dim3(8, 16), 0, stream>>>(t1p, w2, t2p);
    k_conv3_out<<<dim3(16, 16, 2), dim3(16, 16), 0, stream>>>(t2p, w3, out, total);
    k_win_pass<<<dim3(128), dim3(256), 0, stream>>>(total, win_state, 0);
    k_win_pass<<<dim3(128), dim3(256), 0, stream>>>(total, win_state, 1);
    k_win_finish<<<dim3(1), dim3(64), 0, stream>>>(win_state, out);
}